// Round 16
// baseline (140.747 us; speedup 1.0000x reference)
//
#include <hip/hip_runtime.h>
#include <hip/hip_bf16.h>

#define B 8
#define T 1024
#define C 768
#define H 12
#define D 64
#define M (B * T)     // 8192

typedef unsigned short u16;
typedef unsigned int u32;
typedef __attribute__((ext_vector_type(8))) short bf16x8;
typedef __attribute__((ext_vector_type(4))) float f32x4;

__device__ __forceinline__ u16 f2bf(float f) {
  union { float f; u32 u; } c; c.f = f;
  u32 r = c.u + 0x7FFF + ((c.u >> 16) & 1);
  return (u16)(r >> 16);
}

__device__ __forceinline__ void gload16(const void* g, void* l) {
  __builtin_amdgcn_global_load_lds(
      (const __attribute__((address_space(1))) void*)g,
      (__attribute__((address_space(3))) void*)l, 16, 0, 0);
}

// swizzle for 64B LDS rows (4x16B slots)
__device__ __forceinline__ int swzA(int row) {
  return (row & 3) ^ ((row >> 2) & 1);
}

// ---------------- fused prep: x fp32->bf16 convert  +  weight transpose ----------------
__global__ __launch_bounds__(256) void prep_kernel(
    const float* __restrict__ x,
    const float* __restrict__ Wq, const float* __restrict__ Wk,
    const float* __restrict__ Wv, const float* __restrict__ Wo,
    u16* __restrict__ xb, u16* __restrict__ WtQKV, u16* __restrict__ WoT) {
  __shared__ float t[32][33];
  const int bx = blockIdx.x;
  if (bx < 2048) {
    const int n4 = M * C / 4;
    for (int i = bx * 256 + threadIdx.x; i < n4; i += 2048 * 256) {
      float4 v = ((const float4*)x)[i];
      ushort4 o;
      o.x = f2bf(v.x); o.y = f2bf(v.y); o.z = f2bf(v.z); o.w = f2bf(v.w);
      ((ushort4*)xb)[i] = o;
    }
    return;
  }
  const int i = bx - 2048;        // 0..2303
  const int z = i / 576;          // weight index (24*24 tiles each)
  const int rem = i % 576;
  const int k0 = (rem / 24) * 32, n0 = (rem % 24) * 32;
  const float* W = (z == 0) ? Wq : (z == 1) ? Wk : (z == 2) ? Wv : Wo;
  u16* dst = (z < 3) ? (WtQKV + (size_t)z * 768 * 768) : WoT;
  const int tx = threadIdx.x & 31, ty = threadIdx.x >> 5;  // ty 0..7
#pragma unroll
  for (int j = 0; j < 4; j++) {
    int r = ty * 4 + j;
    t[r][tx] = W[(size_t)(k0 + r) * 768 + n0 + tx];
  }
  __syncthreads();
#pragma unroll
  for (int j = 0; j < 4; j++) {
    int r = ty * 4 + j;
    dst[(size_t)(n0 + r) * 768 + k0 + tx] = f2bf(t[tx][r]);
  }
}

// ---------------- bf16 MFMA GEMM (BK=32, BN=128) + bijective XCD chunking ----------------
template <typename OutT, bool ROWBIAS, int NBCOLS>
__global__ __launch_bounds__(256) void gemm_mfma_kernel(
    const u16* __restrict__ A,    // [Mrows][768] bf16
    const u16* __restrict__ Wt,   // [Ncols][768] bf16
    const float* __restrict__ b0, const float* __restrict__ b1,
    OutT* __restrict__ o0, OutT* __restrict__ o1,
    int ldOut, float sc0, float sc1) {
  __shared__ u16 As[128 * 32];
  __shared__ u16 Bs[128 * 32];
  const int tid = threadIdx.x;
  const int w = tid >> 6, l = tid & 63;
  const int g = l >> 4, c = l & 15;
  const int nwg8 = gridDim.x >> 3;
  const int swz = (blockIdx.x & 7) * nwg8 + (blockIdx.x >> 3);
  const int m0 = (swz / NBCOLS) * 128;
  const int n0g = (swz % NBCOLS) * 128;
  const int seg = (!ROWBIAS && n0g >= 768) ? 1 : 0;
  const int n0 = n0g - seg * 768;
  const float* bias = (seg == 0) ? b0 : b1;
  OutT* out = (seg == 0) ? o0 : o1;
  const float sc = (seg == 0) ? sc0 : sc1;
  const int wr = (w >> 1) * 64, wc = (w & 1) * 64;

  f32x4 acc[4][4];
#pragma unroll
  for (int i = 0; i < 4; i++)
#pragma unroll
    for (int j = 0; j < 4; j++) acc[i][j] = f32x4{0.f, 0.f, 0.f, 0.f};

  for (int k0 = 0; k0 < 768; k0 += 32) {
    __syncthreads();
#pragma unroll
    for (int t = 0; t < 2; t++) {
      int ii = w * 2 + t;
      int e16 = ii * 64 + l;
      int row = e16 >> 2, slot = e16 & 3;
      int gs = slot ^ swzA(row);
      gload16(A + (size_t)(m0 + row) * 768 + k0 + gs * 8, (char*)As + ii * 1024);
    }
#pragma unroll
    for (int t = 0; t < 2; t++) {
      int ii = w * 2 + t;
      int e16 = ii * 64 + l;
      int row = e16 >> 2, slot = e16 & 3;
      int gs = slot ^ swzA(row);
      gload16(Wt + (size_t)(n0g + row) * 768 + k0 + gs * 8, (char*)Bs + ii * 1024);
    }
    __syncthreads();

    bf16x8 af[4], bfr[4];
#pragma unroll
    for (int i = 0; i < 4; i++) {
      int row = wr + i * 16 + c;
      int slot = g ^ swzA(row);
      af[i] = *(const bf16x8*)(As + row * 32 + slot * 8);
    }
#pragma unroll
    for (int j = 0; j < 4; j++) {
      int row = wc + j * 16 + c;
      int slot = g ^ swzA(row);
      bfr[j] = *(const bf16x8*)(Bs + row * 32 + slot * 8);
    }
#pragma unroll
    for (int i = 0; i < 4; i++)
#pragma unroll
      for (int j = 0; j < 4; j++)
        acc[i][j] = __builtin_amdgcn_mfma_f32_16x16x32_bf16(af[i], bfr[j], acc[i][j], 0, 0, 0);
  }

  // epilogue (C layout: col = lane&15, row = (lane>>4)*4 + reg)
  float brow[4][4];
  if (ROWBIAS) {
#pragma unroll
    for (int i = 0; i < 4; i++)
#pragma unroll
      for (int r = 0; r < 4; r++)
        brow[i][r] = b0[m0 + wr + i * 16 + g * 4 + r];
  }
#pragma unroll
  for (int j = 0; j < 4; j++) {
    int col = n0 + wc + j * 16 + c;
    float bcol = ROWBIAS ? 0.f : bias[col];
#pragma unroll
    for (int i = 0; i < 4; i++) {
#pragma unroll
      for (int r = 0; r < 4; r++) {
        int row = m0 + wr + i * 16 + g * 4 + r;
        float v = (acc[i][j][r] + (ROWBIAS ? brow[i][r] : bcol)) * sc;
        if constexpr (sizeof(OutT) == 2) {
          ((u16*)out)[(size_t)row * ldOut + col] = f2bf(v);
        } else {
          ((float*)out)[(size_t)row * ldOut + col] = v;
        }
      }
    }
  }
}

// ---------------- bf16 MFMA flash attention (causal), exp2 domain ----------------
// Round-12 proven per-wave math, scaled shell: block = one (b,h) x 128 q rows,
// 8 waves x 16 rows, 512 threads. Halves staging traffic + barriers per q-row
// (36 vs 72 tiles per (b,h)). LDS 65.8 KB -> 2 blocks/CU = 16 waves/CU.
__global__ __launch_bounds__(512) void attn_mfma_kernel(
    const u16* __restrict__ Qb, const u16* __restrict__ Kb,
    const u16* __restrict__ VT, u16* __restrict__ Ob) {
  __shared__ u16 Ks[128 * 64];     // [kv][d]          16 KB
  __shared__ u16 Vs[64 * 128];     // [d][kv] V^T tile 16 KB
  __shared__ u16 Ps[8][16][132];   // per-wave P       33 KB

  const int tid = threadIdx.x;
  const int w = tid >> 6, l = tid & 63;   // w in 0..7
  const int g = l >> 4, c = l & 15;

  // 768 blocks: XCD-chunked (96/XCD = 12 bh), work-descending q within each bh
  const int wg = blockIdx.x;
  const int logical = (wg & 7) * 96 + (wg >> 3);
  const int bh = logical >> 3;
  const int qi = 7 - (logical & 7);
  const int q0 = qi * 128;
  const int b = bh / H, h = bh % H;
  const int qw = q0 + w * 16;

  bf16x8 qf[2];
  {
    size_t base = (size_t)(b * T + qw + c) * C + h * D;
    qf[0] = *(const bf16x8*)(Qb + base + g * 8);
    qf[1] = *(const bf16x8*)(Qb + base + 32 + g * 8);
  }

  f32x4 acc[4];
#pragma unroll
  for (int j = 0; j < 4; j++) acc[j] = f32x4{0.f, 0.f, 0.f, 0.f};
  float m_i[4], l_p[4];  // running max (log2 domain), per-lane partial l
#pragma unroll
  for (int r = 0; r < 4; r++) { m_i[r] = -1e30f; l_p[r] = 0.f; }

  const int nt = q0 / 128 + 1;
  for (int it = 0; it < nt; it++) {
    const int s0 = it * 128;
    __syncthreads();
    // stage K: 1024 16B-chunks over 8 waves (2/thread), rows 128B / 8 slots
#pragma unroll
    for (int t = 0; t < 2; t++) {
      int ii = w * 2 + t;
      int e16 = ii * 64 + l;
      int row = e16 >> 3, slot = e16 & 7;
      int gs = slot ^ (row & 7);
      gload16(Kb + (size_t)(b * T + s0 + row) * C + h * D + gs * 8, (char*)Ks + ii * 1024);
    }
    // stage V^T: 1024 16B-chunks, rows 256B / 16 slots
#pragma unroll
    for (int t = 0; t < 2; t++) {
      int ii = w * 2 + t;
      int e16 = ii * 64 + l;
      int row = e16 >> 4, slot = e16 & 15;
      int gs = slot ^ (row & 15);
      gload16(VT + (size_t)(h * D + row) * M + b * T + s0 + gs * 8, (char*)Vs + ii * 1024);
    }
    __syncthreads();

    const bool active = (s0 <= qw + 15);
    if (active) {
      // S = Q' @ K^T : 8 kv-fragments of 16
      f32x4 s[8];
#pragma unroll
      for (int f = 0; f < 8; f++) s[f] = f32x4{0.f, 0.f, 0.f, 0.f};
      __builtin_amdgcn_s_setprio(1);
#pragma unroll
      for (int f = 0; f < 8; f++) {
        int kvrow = f * 16 + c;
#pragma unroll
        for (int kc = 0; kc < 2; kc++) {
          int slot = (kc * 4 + g) ^ (kvrow & 7);
          bf16x8 kf = *(const bf16x8*)(Ks + kvrow * 64 + slot * 8);
          s[f] = __builtin_amdgcn_mfma_f32_16x16x32_bf16(qf[kc], kf, s[f], 0, 0, 0);
        }
      }
      __builtin_amdgcn_s_setprio(0);
      // causal mask only on partial tiles (wave-uniform)
      const bool partial = (s0 + 127 > qw);
      if (partial) {
#pragma unroll
        for (int r = 0; r < 4; r++) {
          int q = qw + g * 4 + r;
#pragma unroll
          for (int f = 0; f < 8; f++) {
            int kv = s0 + f * 16 + c;
            if (kv > q) s[f][r] = -1e30f;
          }
        }
      }
      // per-row max (log2 domain)
      float mx[4];
#pragma unroll
      for (int r = 0; r < 4; r++) {
        float mr = s[0][r];
#pragma unroll
        for (int f = 1; f < 8; f++) mr = fmaxf(mr, s[f][r]);
        mx[r] = mr;
      }
#pragma unroll
      for (int off = 1; off < 16; off <<= 1)
#pragma unroll
        for (int r = 0; r < 4; r++) mx[r] = fmaxf(mx[r], __shfl_xor(mx[r], off, 64));
      // defer-max: skip rescale when max grew by <= 8 (P bounded by 2^8)
      bool defer = true;
#pragma unroll
      for (int r = 0; r < 4; r++) defer = defer && (mx[r] <= m_i[r] + 8.0f);
      if (!__all(defer)) {
#pragma unroll
        for (int r = 0; r < 4; r++) {
          float mn = fmaxf(m_i[r], mx[r]);
          float rc = exp2f(m_i[r] - mn);
          m_i[r] = mn;
          l_p[r] *= rc;
#pragma unroll
          for (int j = 0; j < 4; j++) acc[j][r] *= rc;
        }
      }
      // P = exp2(S - m), per-lane partial row sum; packed bf16 convert
#pragma unroll
      for (int r = 0; r < 4; r++) {
        float sum = 0.f;
#pragma unroll
        for (int f = 0; f < 8; f++) {
          float p = exp2f(s[f][r] - m_i[r]);
          s[f][r] = p;
          sum += p;
        }
        l_p[r] += sum;
#pragma unroll
        for (int f = 0; f < 8; f += 2) {
          __hip_bfloat162 h2 = __float22bfloat162_rn(make_float2(s[f][r], s[f + 1][r]));
          u32 pk = *(u32*)&h2;
          Ps[w][g * 4 + r][f * 16 + c] = (u16)pk;
          Ps[w][g * 4 + r][(f + 1) * 16 + c] = (u16)(pk >> 16);
        }
      }
      // O += P @ V
      __builtin_amdgcn_s_setprio(1);
#pragma unroll
      for (int kc = 0; kc < 4; kc++) {
        bf16x8 pf = *(const bf16x8*)(&Ps[w][c][kc * 32 + g * 8]);
#pragma unroll
        for (int j = 0; j < 4; j++) {
          bf16x8 vf = *(const bf16x8*)(Vs + (j * 16 + c) * 128 + (((kc * 4 + g) ^ c) * 8));
          acc[j] = __builtin_amdgcn_mfma_f32_16x16x32_bf16(pf, vf, acc[j], 0, 0, 0);
        }
      }
      __builtin_amdgcn_s_setprio(0);
    }
  }

  // epilogue: reduce l across the 16-lane group, normalize, store bf16
  float inv[4];
#pragma unroll
  for (int r = 0; r < 4; r++) {
    float v = l_p[r];
#pragma unroll
    for (int off = 1; off < 16; off <<= 1) v += __shfl_xor(v, off, 64);
    inv[r] = 1.f / v;
  }
#pragma unroll
  for (int j = 0; j < 4; j++) {
#pragma unroll
    for (int r = 0; r < 4; r++) {
      int row = qw + g * 4 + r;
      int col = j * 16 + c;
      Ob[(size_t)(b * T + row) * C + h * D + col] = f2bf(acc[j][r] * inv[r]);
    }
  }
}

extern "C" void kernel_launch(void* const* d_in, const int* in_sizes, int n_in,
                              void* d_out, int out_size, void* d_ws, size_t ws_size,
                              hipStream_t stream) {
  const float* x  = (const float*)d_in[0];
  const float* Wq = (const float*)d_in[2];
  const float* bq = (const float*)d_in[3];
  const float* Wk = (const float*)d_in[4];
  const float* bk = (const float*)d_in[5];
  const float* Wv = (const float*)d_in[6];
  const float* bv = (const float*)d_in[7];
  const float* Wo = (const float*)d_in[8];
  const float* bo = (const float*)d_in[9];
  float* out = (float*)d_out;

  const size_t MC2 = (size_t)M * C * 2;  // bf16 activation bytes = 12.58 MB
  char* ws = (char*)d_ws;
  u16* xb    = (u16*)(ws);
  u16* WtQKV = (u16*)(ws + MC2);
  u16* WoT   = (u16*)(ws + MC2 + 3538944);
  u16* Qb    = (u16*)(ws + MC2 + 3538944 + 1179648);
  u16* Kb    = (u16*)((char*)Qb + MC2);
  u16* VT    = (u16*)((char*)Kb + MC2);   // [768 ch][8192 tok] = V^T
  u16* Ob    = (u16*)((char*)VT + MC2);
  u16* WvT   = WtQKV + 2 * 768 * 768;

  // Q pre-scale: (1/sqrt(D)) * log2(e) -> softmax in exp2 domain
  const float qscale = 0.125f * 1.4426950408889634f;

  // 1) prep: xconv (2048 blocks) + wtrans (2304 blocks)
  prep_kernel<<<4352, 256, 0, stream>>>(x, Wq, Wk, Wv, Wo, xb, WtQKV, WoT);
  // 2) fused QK GEMM: 768 blocks, 12 col-panels, XCD-chunked
  gemm_mfma_kernel<u16, false, 12><<<768, 256, 0, stream>>>(
      xb, WtQKV, bq, bk, Qb, Kb, 768, qscale, 1.f);
  // 3) V^T GEMM: 384 blocks, 64 token-panels, row bias, XCD-chunked
  gemm_mfma_kernel<u16, true, 64><<<384, 256, 0, stream>>>(
      WvT, xb, bv, bv, VT, VT, M, 1.f, 1.f);
  // 4) attention: 768 blocks x 512 threads (8 waves, 128 q rows)
  attn_mfma_kernel<<<768, 512, 0, stream>>>(Qb, Kb, VT, Ob);
  // 5) output projection: 384 blocks, 6 col-panels, XCD-chunked
  gemm_mfma_kernel<float, false, 6><<<384, 256, 0, stream>>>(
      Ob, WoT, bo, bo, out, out, 768, 1.f, 1.f);
}

// Round 17
// 135.064 us; speedup vs baseline: 1.0421x; 1.0421x over previous
//
#include <hip/hip_runtime.h>
#include <hip/hip_bf16.h>

#define B 8
#define T 1024
#define C 768
#define H 12
#define D 64
#define M (B * T)     // 8192

typedef unsigned short u16;
typedef unsigned int u32;
typedef __attribute__((ext_vector_type(8))) short bf16x8;
typedef __attribute__((ext_vector_type(4))) float f32x4;

__device__ __forceinline__ u16 f2bf(float f) {
  union { float f; u32 u; } c; c.f = f;
  u32 r = c.u + 0x7FFF + ((c.u >> 16) & 1);
  return (u16)(r >> 16);
}

__device__ __forceinline__ void gload16(const void* g, void* l) {
  __builtin_amdgcn_global_load_lds(
      (const __attribute__((address_space(1))) void*)g,
      (__attribute__((address_space(3))) void*)l, 16, 0, 0);
}

// swizzle for 64B LDS rows (4x16B slots)
__device__ __forceinline__ int swzA(int row) {
  return (row & 3) ^ ((row >> 2) & 1);
}

// ---------------- fused prep: x fp32->bf16 convert  +  weight transpose ----------------
__global__ __launch_bounds__(256) void prep_kernel(
    const float* __restrict__ x,
    const float* __restrict__ Wq, const float* __restrict__ Wk,
    const float* __restrict__ Wv, const float* __restrict__ Wo,
    u16* __restrict__ xb, u16* __restrict__ WtQKV, u16* __restrict__ WoT) {
  __shared__ float t[32][33];
  const int bx = blockIdx.x;
  if (bx < 2048) {
    const int n4 = M * C / 4;
    for (int i = bx * 256 + threadIdx.x; i < n4; i += 2048 * 256) {
      float4 v = ((const float4*)x)[i];
      ushort4 o;
      o.x = f2bf(v.x); o.y = f2bf(v.y); o.z = f2bf(v.z); o.w = f2bf(v.w);
      ((ushort4*)xb)[i] = o;
    }
    return;
  }
  const int i = bx - 2048;        // 0..2303
  const int z = i / 576;          // weight index (24*24 tiles each)
  const int rem = i % 576;
  const int k0 = (rem / 24) * 32, n0 = (rem % 24) * 32;
  const float* W = (z == 0) ? Wq : (z == 1) ? Wk : (z == 2) ? Wv : Wo;
  u16* dst = (z < 3) ? (WtQKV + (size_t)z * 768 * 768) : WoT;
  const int tx = threadIdx.x & 31, ty = threadIdx.x >> 5;  // ty 0..7
#pragma unroll
  for (int j = 0; j < 4; j++) {
    int r = ty * 4 + j;
    t[r][tx] = W[(size_t)(k0 + r) * 768 + n0 + tx];
  }
  __syncthreads();
#pragma unroll
  for (int j = 0; j < 4; j++) {
    int r = ty * 4 + j;
    dst[(size_t)(n0 + r) * 768 + k0 + tx] = f2bf(t[tx][r]);
  }
}

// ---------------- bf16 MFMA GEMM (BK=32, BN=128) + bijective XCD chunking ----------------
// 1D grid (multiple of 8): swz = (bx&7)*(nwg/8) + (bx>>3);
// m0 = (swz/NBCOLS)*128, n0g = (swz%NBCOLS)*128.
template <typename OutT, bool ROWBIAS, int NBCOLS>
__global__ __launch_bounds__(256) void gemm_mfma_kernel(
    const u16* __restrict__ A,    // [Mrows][768] bf16
    const u16* __restrict__ Wt,   // [Ncols][768] bf16
    const float* __restrict__ b0, const float* __restrict__ b1,
    OutT* __restrict__ o0, OutT* __restrict__ o1,
    int ldOut, float sc0, float sc1) {
  __shared__ u16 As[128 * 32];
  __shared__ u16 Bs[128 * 32];
  const int tid = threadIdx.x;
  const int w = tid >> 6, l = tid & 63;
  const int g = l >> 4, c = l & 15;
  const int nwg8 = gridDim.x >> 3;
  const int swz = (blockIdx.x & 7) * nwg8 + (blockIdx.x >> 3);
  const int m0 = (swz / NBCOLS) * 128;
  const int n0g = (swz % NBCOLS) * 128;
  const int seg = (!ROWBIAS && n0g >= 768) ? 1 : 0;
  const int n0 = n0g - seg * 768;
  const float* bias = (seg == 0) ? b0 : b1;
  OutT* out = (seg == 0) ? o0 : o1;
  const float sc = (seg == 0) ? sc0 : sc1;
  const int wr = (w >> 1) * 64, wc = (w & 1) * 64;

  f32x4 acc[4][4];
#pragma unroll
  for (int i = 0; i < 4; i++)
#pragma unroll
    for (int j = 0; j < 4; j++) acc[i][j] = f32x4{0.f, 0.f, 0.f, 0.f};

  for (int k0 = 0; k0 < 768; k0 += 32) {
    __syncthreads();
#pragma unroll
    for (int t = 0; t < 2; t++) {
      int ii = w * 2 + t;
      int e16 = ii * 64 + l;
      int row = e16 >> 2, slot = e16 & 3;
      int gs = slot ^ swzA(row);
      gload16(A + (size_t)(m0 + row) * 768 + k0 + gs * 8, (char*)As + ii * 1024);
    }
#pragma unroll
    for (int t = 0; t < 2; t++) {
      int ii = w * 2 + t;
      int e16 = ii * 64 + l;
      int row = e16 >> 2, slot = e16 & 3;
      int gs = slot ^ swzA(row);
      gload16(Wt + (size_t)(n0g + row) * 768 + k0 + gs * 8, (char*)Bs + ii * 1024);
    }
    __syncthreads();

    bf16x8 af[4], bfr[4];
#pragma unroll
    for (int i = 0; i < 4; i++) {
      int row = wr + i * 16 + c;
      int slot = g ^ swzA(row);
      af[i] = *(const bf16x8*)(As + row * 32 + slot * 8);
    }
#pragma unroll
    for (int j = 0; j < 4; j++) {
      int row = wc + j * 16 + c;
      int slot = g ^ swzA(row);
      bfr[j] = *(const bf16x8*)(Bs + row * 32 + slot * 8);
    }
#pragma unroll
    for (int i = 0; i < 4; i++)
#pragma unroll
      for (int j = 0; j < 4; j++)
        acc[i][j] = __builtin_amdgcn_mfma_f32_16x16x32_bf16(af[i], bfr[j], acc[i][j], 0, 0, 0);
  }

  // epilogue (C layout: col = lane&15, row = (lane>>4)*4 + reg)
  float brow[4][4];
  if (ROWBIAS) {
#pragma unroll
    for (int i = 0; i < 4; i++)
#pragma unroll
      for (int r = 0; r < 4; r++)
        brow[i][r] = b0[m0 + wr + i * 16 + g * 4 + r];
  }
#pragma unroll
  for (int j = 0; j < 4; j++) {
    int col = n0 + wc + j * 16 + c;
    float bcol = ROWBIAS ? 0.f : bias[col];
#pragma unroll
    for (int i = 0; i < 4; i++) {
#pragma unroll
      for (int r = 0; r < 4; r++) {
        int row = m0 + wr + i * 16 + g * 4 + r;
        float v = (acc[i][j][r] + (ROWBIAS ? brow[i][r] : bcol)) * sc;
        if constexpr (sizeof(OutT) == 2) {
          ((u16*)out)[(size_t)row * ldOut + col] = f2bf(v);
        } else {
          ((float*)out)[(size_t)row * ldOut + col] = v;
        }
      }
    }
  }
}

// ---------------- bf16 MFMA flash attention (causal), exp2 domain ----------------
// Round-12/15 proven version (4 waves x 16 q rows, KV tiles of 128,
// 2 barriers/tile, K+V^T LDS staging via gload16, Ps separate, setprio).
__global__ __launch_bounds__(256) void attn_mfma_kernel(
    const u16* __restrict__ Qb, const u16* __restrict__ Kb,
    const u16* __restrict__ VT, u16* __restrict__ Ob) {
  __shared__ u16 Ks[128 * 64];     // [kv][d]
  __shared__ u16 Vs[64 * 128];     // [d][kv] (V^T tile)
  __shared__ u16 Ps[4][16][132];   // per-wave P [qrow][kv], pad 132

  const int tid = threadIdx.x;
  const int w = tid >> 6, l = tid & 63;
  const int g = l >> 4, c = l & 15;

  // XCD-chunked, work-descending launch order (1536 blocks, 192 per XCD)
  const int wg = blockIdx.x;
  const int logical = (wg & 7) * 192 + (wg >> 3);
  const int bh = logical >> 4;
  const int qi = 15 - (logical & 15);
  const int q0 = qi * 64;
  const int b = bh / H, h = bh % H;
  const int qw = q0 + w * 16;

  bf16x8 qf[2];
  {
    size_t base = (size_t)(b * T + qw + c) * C + h * D;
    qf[0] = *(const bf16x8*)(Qb + base + g * 8);
    qf[1] = *(const bf16x8*)(Qb + base + 32 + g * 8);
  }

  f32x4 acc[4];
#pragma unroll
  for (int j = 0; j < 4; j++) acc[j] = f32x4{0.f, 0.f, 0.f, 0.f};
  float m_i[4], l_p[4];  // running max (log2 domain), per-lane partial l
#pragma unroll
  for (int r = 0; r < 4; r++) { m_i[r] = -1e30f; l_p[r] = 0.f; }

  const int nt = q0 / 128 + 1;
  for (int it = 0; it < nt; it++) {
    const int s0 = it * 128;
    __syncthreads();
    // stage K: 1024 16B-chunks, rows 128B / 8 slots, source pre-swizzled
#pragma unroll
    for (int t = 0; t < 4; t++) {
      int ii = w * 4 + t;
      int e16 = ii * 64 + l;
      int row = e16 >> 3, slot = e16 & 7;
      int gs = slot ^ (row & 7);
      gload16(Kb + (size_t)(b * T + s0 + row) * C + h * D + gs * 8, (char*)Ks + ii * 1024);
    }
    // stage V^T: 1024 16B-chunks, rows 256B / 16 slots, source pre-swizzled
#pragma unroll
    for (int t = 0; t < 4; t++) {
      int ii = w * 4 + t;
      int e16 = ii * 64 + l;
      int row = e16 >> 4, slot = e16 & 15;
      int gs = slot ^ (row & 15);
      gload16(VT + (size_t)(h * D + row) * M + b * T + s0 + gs * 8, (char*)Vs + ii * 1024);
    }
    __syncthreads();

    const bool active = (s0 <= qw + 15);
    if (active) {
      // S = Q' @ K^T : 8 kv-fragments of 16
      f32x4 s[8];
#pragma unroll
      for (int f = 0; f < 8; f++) s[f] = f32x4{0.f, 0.f, 0.f, 0.f};
      __builtin_amdgcn_s_setprio(1);
#pragma unroll
      for (int f = 0; f < 8; f++) {
        int kvrow = f * 16 + c;
#pragma unroll
        for (int kc = 0; kc < 2; kc++) {
          int slot = (kc * 4 + g) ^ (kvrow & 7);
          bf16x8 kf = *(const bf16x8*)(Ks + kvrow * 64 + slot * 8);
          s[f] = __builtin_amdgcn_mfma_f32_16x16x32_bf16(qf[kc], kf, s[f], 0, 0, 0);
        }
      }
      __builtin_amdgcn_s_setprio(0);
      // causal mask only on partial tiles (wave-uniform)
      const bool partial = (s0 + 127 > qw);
      if (partial) {
#pragma unroll
        for (int r = 0; r < 4; r++) {
          int q = qw + g * 4 + r;
#pragma unroll
          for (int f = 0; f < 8; f++) {
            int kv = s0 + f * 16 + c;
            if (kv > q) s[f][r] = -1e30f;
          }
        }
      }
      // per-row max (log2 domain)
      float mx[4];
#pragma unroll
      for (int r = 0; r < 4; r++) {
        float mr = s[0][r];
#pragma unroll
        for (int f = 1; f < 8; f++) mr = fmaxf(mr, s[f][r]);
        mx[r] = mr;
      }
#pragma unroll
      for (int off = 1; off < 16; off <<= 1)
#pragma unroll
        for (int r = 0; r < 4; r++) mx[r] = fmaxf(mx[r], __shfl_xor(mx[r], off, 64));
      // defer-max: skip rescale when max grew by <= 8 (P bounded by 2^8)
      bool defer = true;
#pragma unroll
      for (int r = 0; r < 4; r++) defer = defer && (mx[r] <= m_i[r] + 8.0f);
      if (!__all(defer)) {
#pragma unroll
        for (int r = 0; r < 4; r++) {
          float mn = fmaxf(m_i[r], mx[r]);
          float rc = exp2f(m_i[r] - mn);
          m_i[r] = mn;
          l_p[r] *= rc;
#pragma unroll
          for (int j = 0; j < 4; j++) acc[j][r] *= rc;
        }
      }
      // P = exp2(S - m), per-lane partial row sum; packed bf16 convert
#pragma unroll
      for (int r = 0; r < 4; r++) {
        float sum = 0.f;
#pragma unroll
        for (int f = 0; f < 8; f++) {
          float p = exp2f(s[f][r] - m_i[r]);
          s[f][r] = p;
          sum += p;
        }
        l_p[r] += sum;
#pragma unroll
        for (int f = 0; f < 8; f += 2) {
          __hip_bfloat162 h2 = __float22bfloat162_rn(make_float2(s[f][r], s[f + 1][r]));
          u32 pk = *(u32*)&h2;
          Ps[w][g * 4 + r][f * 16 + c] = (u16)pk;
          Ps[w][g * 4 + r][(f + 1) * 16 + c] = (u16)(pk >> 16);
        }
      }
      // O += P @ V
      __builtin_amdgcn_s_setprio(1);
#pragma unroll
      for (int kc = 0; kc < 4; kc++) {
        bf16x8 pf = *(const bf16x8*)(&Ps[w][c][kc * 32 + g * 8]);
#pragma unroll
        for (int j = 0; j < 4; j++) {
          bf16x8 vf = *(const bf16x8*)(Vs + (j * 16 + c) * 128 + (((kc * 4 + g) ^ c) * 8));
          acc[j] = __builtin_amdgcn_mfma_f32_16x16x32_bf16(pf, vf, acc[j], 0, 0, 0);
        }
      }
      __builtin_amdgcn_s_setprio(0);
    }
  }

  // epilogue: reduce l across the 16-lane group, normalize, store bf16
  float inv[4];
#pragma unroll
  for (int r = 0; r < 4; r++) {
    float v = l_p[r];
#pragma unroll
    for (int off = 1; off < 16; off <<= 1) v += __shfl_xor(v, off, 64);
    inv[r] = 1.f / v;
  }
#pragma unroll
  for (int j = 0; j < 4; j++) {
#pragma unroll
    for (int r = 0; r < 4; r++) {
      int row = qw + g * 4 + r;
      int col = j * 16 + c;
      Ob[(size_t)(b * T + row) * C + h * D + col] = f2bf(acc[j][r] * inv[r]);
    }
  }
}

extern "C" void kernel_launch(void* const* d_in, const int* in_sizes, int n_in,
                              void* d_out, int out_size, void* d_ws, size_t ws_size,
                              hipStream_t stream) {
  const float* x  = (const float*)d_in[0];
  const float* Wq = (const float*)d_in[2];
  const float* bq = (const float*)d_in[3];
  const float* Wk = (const float*)d_in[4];
  const float* bk = (const float*)d_in[5];
  const float* Wv = (const float*)d_in[6];
  const float* bv = (const float*)d_in[7];
  const float* Wo = (const float*)d_in[8];
  const float* bo = (const float*)d_in[9];
  float* out = (float*)d_out;

  const size_t MC2 = (size_t)M * C * 2;  // bf16 activation bytes = 12.58 MB
  char* ws = (char*)d_ws;
  u16* xb    = (u16*)(ws);
  u16* WtQKV = (u16*)(ws + MC2);
  u16* WoT   = (u16*)(ws + MC2 + 3538944);
  u16* Qb    = (u16*)(ws + MC2 + 3538944 + 1179648);
  u16* Kb    = (u16*)((char*)Qb + MC2);
  u16* VT    = (u16*)((char*)Kb + MC2);   // [768 ch][8192 tok] = V^T
  u16* Ob    = (u16*)((char*)VT + MC2);
  u16* WvT   = WtQKV + 2 * 768 * 768;

  // Q pre-scale: (1/sqrt(D)) * log2(e) -> softmax in exp2 domain
  const float qscale = 0.125f * 1.4426950408889634f;

  // 1) prep: xconv (2048 blocks) + wtrans (2304 blocks)
  prep_kernel<<<4352, 256, 0, stream>>>(x, Wq, Wk, Wv, Wo, xb, WtQKV, WoT);
  // 2) fused QK GEMM: 768 blocks, 12 col-panels, XCD-chunked
  gemm_mfma_kernel<u16, false, 12><<<768, 256, 0, stream>>>(
      xb, WtQKV, bq, bk, Qb, Kb, 768, qscale, 1.f);
  // 3) V^T GEMM: 384 blocks, 64 token-panels, row bias, XCD-chunked
  gemm_mfma_kernel<u16, true, 64><<<384, 256, 0, stream>>>(
      WvT, xb, bv, bv, VT, VT, M, 1.f, 1.f);
  // 4) attention
  attn_mfma_kernel<<<1536, 256, 0, stream>>>(Qb, Kb, VT, Ob);
  // 5) output projection: 384 blocks, 6 col-panels, XCD-chunked
  gemm_mfma_kernel<float, false, 6><<<384, 256, 0, stream>>>(
      Ob, WoT, bo, bo, out, out, 768, 1.f, 1.f);
}